// Round 5
// baseline (428.662 us; speedup 1.0000x reference)
//
#include <hip/hip_runtime.h>
#include <hip/hip_bf16.h>
#include <math.h>

typedef __bf16 bf16x8 __attribute__((ext_vector_type(8)));
typedef __bf16 bf16x4 __attribute__((ext_vector_type(4)));
typedef float  f32x4  __attribute__((ext_vector_type(4)));

constexpr int D   = 128;
constexpr int LQ  = 2048;
constexpr int SK  = 2048;
constexpr int BM  = 256;  // queries per block (8 waves x 32 rows)
constexpr int BN  = 64;   // keys per iteration
constexpr int NKV = 16;   // B*H distinct KV heads
constexpr int NT  = SK / BN;  // 32

__device__ __forceinline__ void load_lds16(const void* g, void* l) {
  __builtin_amdgcn_global_load_lds((const __attribute__((address_space(1))) unsigned*)g,
                                   (__attribute__((address_space(3))) unsigned*)l, 16, 0, 0);
}

__device__ __forceinline__ f32x4 vmax4(f32x4 a, f32x4 b) {
  f32x4 r;
  r[0] = fmaxf(a[0], b[0]); r[1] = fmaxf(a[1], b[1]);
  r[2] = fmaxf(a[2], b[2]); r[3] = fmaxf(a[3], b[3]);
  return r;
}

// ---- prologue A: K fp32 -> Khi/Klo bf16 (elementwise, coalesced)
__global__ __launch_bounds__(256) void conv_k(const float* __restrict__ k,
                                              __bf16* __restrict__ khi,
                                              __bf16* __restrict__ klo) {
  const size_t i = ((size_t)blockIdx.x * 256 + threadIdx.x) * 4;
  f32x4 a = *(const f32x4*)(k + i);
  bf16x4 hi, lo;
#pragma unroll
  for (int j = 0; j < 4; ++j) {
    hi[j] = (__bf16)a[j];
    lo[j] = (__bf16)(a[j] - (float)hi[j]);
  }
  *(bf16x4*)(khi + i) = hi;
  *(bf16x4*)(klo + i) = lo;
}

// ---- prologue B: V fp32 [bh][s][d] -> Vt bf16 [bh][d][s'] where s' is
// kappa-PERMUTED within each 32-key group: physical slot pi = 8q+4h+r holds
// key w = 16h+4q+r. PV A-fragment then = ONE b128 read with the
// conflict-free chunk pattern (verified round 4: SQ_LDS_BANK_CONFLICT = 0).
__global__ __launch_bounds__(256) void transpose_v(const float* __restrict__ v,
                                                   __bf16* __restrict__ vt) {
  const int b    = blockIdx.x;          // 1024 = 16 bh x 64
  const int bh   = b >> 6;
  const int t2   = (b & 63) * 256 + threadIdx.x;  // 0..16383 within bh
  const int d    = t2 & 127;
  const int slot = t2 >> 7;             // 0..127
  const int G    = slot >> 1;           // 32-key group 0..63
  const int h2   = slot & 1;            // which half of the group's slots
  const float* src = v + ((size_t)bh * SK + 32 * G) * D + d;
  bf16x8 o0, o1;
  // dst slot idx = 8*qq+4*h+r (pi = 16*h2 + idx, q = 2*h2+qq) <- key 16h+4q+r
#pragma unroll
  for (int qq = 0; qq < 2; ++qq)
#pragma unroll
    for (int h = 0; h < 2; ++h)
#pragma unroll
      for (int r = 0; r < 4; ++r) {
        const int idx = 8 * qq + 4 * h + r;
        const int w   = 16 * h + 4 * (2 * h2 + qq) + r;
        const __bf16 val = (__bf16)src[(size_t)w * D];
        if (idx < 8) o0[idx] = val; else o1[idx - 8] = val;
      }
  __bf16* dst = vt + ((size_t)bh * D + d) * SK + 32 * G + 16 * h2;
  *(bf16x8*)dst = o0;
  *(bf16x8*)(dst + 8) = o1;
}

// ---- main: flash GQA, 8 waves x 32 q-rows. Round-2 envelope:
// __launch_bounds__(512,2) (256-reg cap, no spills), double-buffered LDS
// (96KB -> 1 block/CU, structural: 2 blocks needs <=128 VGPR which spills),
// prefetch-one-tile-ahead, ONE vmcnt(0)+barrier per iter.
// This round: the whole iteration is ONE BRANCHLESS basic block so hipcc's
// scheduler can interleave MFMA and VALU (round-4's __any/setprio branches
// walled softmax VALU off from MFMA clusters -> no overlap, regression).
// Work is u-split into a 4-stage pipeline: QK(u0) -> QK(u1)||softmax(u0)
// -> PV(u0)||softmax(u1) -> PV(u1). No setprio (lockstep waves: m190 regime).
__global__ __launch_bounds__(512, 2)
void gqa_fwd(const float* __restrict__ qg, const __bf16* __restrict__ khi_g,
             const __bf16* __restrict__ klo_g, const __bf16* __restrict__ vt_g,
             float* __restrict__ outg)
{
  __shared__ alignas(16) __bf16 Kh[2][BN * D];   // 2 x 16KB
  __shared__ alignas(16) __bf16 Kl[2][BN * D];   // 2 x 16KB
  __shared__ alignas(16) __bf16 Vs[2][D * BN];   // 2 x 16KB  (total 96KB)

  // XCD swizzle: 64 blocks per XCD, each XCD owns 2 KV heads (~3MB L2 set).
  const int bid   = blockIdx.x;
  const int xcd   = bid & 7;
  const int idx   = bid >> 3;           // 0..63
  const int bh    = 2 * xcd + (idx & 1);
  const int grp   = (idx >> 1) & 3;
  const int qtile = idx >> 3;           // 0..7
  const int bhg   = bh * 4 + grp;

  const int tid  = threadIdx.x;
  const int wave = tid >> 6;            // 0..7
  const int lane = tid & 63;
  const int i16  = lane & 15;
  const int quad = lane >> 4;

  const float*  qbase = qg + (size_t)bhg * (LQ * D) + (size_t)(qtile * BM) * D;
  const __bf16* khb   = khi_g + (size_t)bh * (SK * D);
  const __bf16* klb   = klo_g + (size_t)bh * (SK * D);
  const __bf16* vtb   = vt_g + (size_t)bh * (D * SK);   // [d][s-permuted]

  // per-wave staging: 6 x global_load_lds(16B), src-swizzled, linear dest
  auto stage = [&](int s0, int buf) {
#pragma unroll
    for (int c = 0; c < 2; ++c) {
      const int wc   = 2 * wave + c;          // chunk 0..15 (1KB each)
      const int srow = wc * 4 + (lane >> 4);  // K: 4 rows of 256B per chunk
      const int jk   = (lane & 15) ^ (srow & 15);
      load_lds16(khb + (size_t)(s0 + srow) * D + 8 * jk, (char*)&Kh[buf][0] + wc * 1024);
      load_lds16(klb + (size_t)(s0 + srow) * D + 8 * jk, (char*)&Kl[buf][0] + wc * 1024);
      const int drow = wc * 8 + (lane >> 3);  // V: 8 rows of 128B per chunk
      const int jv   = (lane & 7) ^ (drow & 7);
      load_lds16(vtb + (size_t)drow * SK + s0 + 8 * jv, (char*)&Vs[buf][0] + wc * 1024);
    }
  };

  // prologue: stage tile 0 into buf 0 (overlaps the Q-fragment load below)
  stage(0, 0);

  // ---- Q fragments, persistent hi/lo, pre-scaled by log2(e) for exp2 softmax
  constexpr float LOG2E = 1.44269504089f;
  bf16x8 qhi[2][4], qlo[2][4];
#pragma unroll
  for (int u = 0; u < 2; ++u) {
    const float* qp = qbase + (size_t)(32 * wave + 16 * u + i16) * D + 8 * quad;
#pragma unroll
    for (int t = 0; t < 4; ++t) {
      f32x4 a = *(const f32x4*)(qp + 32 * t);
      f32x4 b = *(const f32x4*)(qp + 32 * t + 4);
#pragma unroll
      for (int j = 0; j < 4; ++j) {
        const float a2 = a[j] * LOG2E;
        const float b2 = b[j] * LOG2E;
        qhi[u][t][j]     = (__bf16)a2;
        qlo[u][t][j]     = (__bf16)(a2 - (float)qhi[u][t][j]);
        qhi[u][t][j + 4] = (__bf16)b2;
        qlo[u][t][j + 4] = (__bf16)(b2 - (float)qhi[u][t][j + 4]);
      }
    }
  }

  f32x4 o_acc[2][8];
#pragma unroll
  for (int u = 0; u < 2; ++u)
#pragma unroll
    for (int c = 0; c < 8; ++c) o_acc[u][c] = (f32x4){0.f, 0.f, 0.f, 0.f};
  float m_r[2] = {-INFINITY, -INFINITY};
  float l_r[2] = {0.f, 0.f};

  asm volatile("s_waitcnt vmcnt(0)" ::: "memory");
  __syncthreads();

  for (int it = 0; it < NT; ++it) {
    const int cur = it & 1;
    const __bf16* khc = &Kh[cur][0];
    const __bf16* klc = &Kl[cur][0];
    const __bf16* vsc = &Vs[cur][0];

    // unconditional staging with wrap (last iter re-stages tile 0: benign,
    // keeps the loop body a single branchless basic block)
    stage(((it + 1) & (NT - 1)) * BN, cur ^ 1);

    // ---- stage 1: S^T(u=0) = K Q0^T (hi/lo bf16 split)
    f32x4 s0[4], s1[4];
#pragma unroll
    for (int n = 0; n < 4; ++n) s0[n] = (f32x4){0.f, 0.f, 0.f, 0.f};
#pragma unroll
    for (int n = 0; n < 4; ++n) {
#pragma unroll
      for (int t = 0; t < 4; ++t) {
        const int ke = (16 * n + i16) * 128 + 8 * ((4 * t + quad) ^ i16);
        bf16x8 kh = *(const bf16x8*)&khc[ke];
        bf16x8 kl = *(const bf16x8*)&klc[ke];
        s0[n] = __builtin_amdgcn_mfma_f32_16x16x32_bf16(kh, qhi[0][t], s0[n], 0, 0, 0);
        s0[n] = __builtin_amdgcn_mfma_f32_16x16x32_bf16(kh, qlo[0][t], s0[n], 0, 0, 0);
        s0[n] = __builtin_amdgcn_mfma_f32_16x16x32_bf16(kl, qhi[0][t], s0[n], 0, 0, 0);
      }
    }

    // ---- stage 2: QK(u=1) MFMAs; softmax(u=0) VALU interleaves (same BB)
#pragma unroll
    for (int n = 0; n < 4; ++n) s1[n] = (f32x4){0.f, 0.f, 0.f, 0.f};
#pragma unroll
    for (int n = 0; n < 4; ++n) {
#pragma unroll
      for (int t = 0; t < 4; ++t) {
        const int ke = (16 * n + i16) * 128 + 8 * ((4 * t + quad) ^ i16);
        bf16x8 kh = *(const bf16x8*)&khc[ke];
        bf16x8 kl = *(const bf16x8*)&klc[ke];
        s1[n] = __builtin_amdgcn_mfma_f32_16x16x32_bf16(kh, qhi[1][t], s1[n], 0, 0, 0);
        s1[n] = __builtin_amdgcn_mfma_f32_16x16x32_bf16(kh, qlo[1][t], s1[n], 0, 0, 0);
        s1[n] = __builtin_amdgcn_mfma_f32_16x16x32_bf16(kl, qhi[1][t], s1[n], 0, 0, 0);
      }
    }

    // softmax(u=0), branchless (alpha=1.0 when max unchanged; mul anyway)
    bf16x8 pb0[2], pb1[2];
    {
      f32x4 vm = vmax4(vmax4(s0[0], s0[1]), vmax4(s0[2], s0[3]));
      float mx = fmaxf(fmaxf(vm[0], vm[1]), fmaxf(vm[2], vm[3]));
      mx = fmaxf(mx, __shfl_xor(mx, 16, 64));
      mx = fmaxf(mx, __shfl_xor(mx, 32, 64));
      const float mnew  = fmaxf(m_r[0], mx);
      const float alpha = exp2f(m_r[0] - mnew);
      m_r[0] = mnew;
      f32x4 rs4 = (f32x4){0.f, 0.f, 0.f, 0.f};
#pragma unroll
      for (int t = 0; t < 2; ++t)
#pragma unroll
        for (int h = 0; h < 2; ++h)
#pragma unroll
          for (int r = 0; r < 4; ++r) {
            const float p   = exp2f(s0[2 * t + h][r] - mnew);
            const __bf16 pv = (__bf16)p;
            pb0[t][4 * h + r] = pv;
            rs4[r] += (float)pv;   // l consistent with bf16 P fed to P*V
          }
      float rs = (rs4[0] + rs4[1]) + (rs4[2] + rs4[3]);
      rs += __shfl_xor(rs, 16, 64);
      rs += __shfl_xor(rs, 32, 64);
      l_r[0] = l_r[0] * alpha + rs;
#pragma unroll
      for (int c = 0; c < 8; ++c) o_acc[0][c] = o_acc[0][c] * alpha;
    }

    // ---- stage 3: PV(u=0) MFMAs; softmax(u=1) VALU interleaves (same BB)
#pragma unroll
    for (int c = 0; c < 8; ++c) {
      const int row = 16 * c + i16;
#pragma unroll
      for (int t = 0; t < 2; ++t) {
        bf16x8 av = *(const bf16x8*)&vsc[row * 64 + 8 * ((4 * t + quad) ^ (i16 & 7))];
        o_acc[0][c] = __builtin_amdgcn_mfma_f32_16x16x32_bf16(av, pb0[t], o_acc[0][c], 0, 0, 0);
      }
    }

    // softmax(u=1)
    {
      f32x4 vm = vmax4(vmax4(s1[0], s1[1]), vmax4(s1[2], s1[3]));
      float mx = fmaxf(fmaxf(vm[0], vm[1]), fmaxf(vm[2], vm[3]));
      mx = fmaxf(mx, __shfl_xor(mx, 16, 64));
      mx = fmaxf(mx, __shfl_xor(mx, 32, 64));
      const float mnew  = fmaxf(m_r[1], mx);
      const float alpha = exp2f(m_r[1] - mnew);
      m_r[1] = mnew;
      f32x4 rs4 = (f32x4){0.f, 0.f, 0.f, 0.f};
#pragma unroll
      for (int t = 0; t < 2; ++t)
#pragma unroll
        for (int h = 0; h < 2; ++h)
#pragma unroll
          for (int r = 0; r < 4; ++r) {
            const float p   = exp2f(s1[2 * t + h][r] - mnew);
            const __bf16 pv = (__bf16)p;
            pb1[t][4 * h + r] = pv;
            rs4[r] += (float)pv;
          }
      float rs = (rs4[0] + rs4[1]) + (rs4[2] + rs4[3]);
      rs += __shfl_xor(rs, 16, 64);
      rs += __shfl_xor(rs, 32, 64);
      l_r[1] = l_r[1] * alpha + rs;
#pragma unroll
      for (int c = 0; c < 8; ++c) o_acc[1][c] = o_acc[1][c] * alpha;
    }

    // ---- stage 4: PV(u=1)
#pragma unroll
    for (int c = 0; c < 8; ++c) {
      const int row = 16 * c + i16;
#pragma unroll
      for (int t = 0; t < 2; ++t) {
        bf16x8 av = *(const bf16x8*)&vsc[row * 64 + 8 * ((4 * t + quad) ^ (i16 & 7))];
        o_acc[1][c] = __builtin_amdgcn_mfma_f32_16x16x32_bf16(av, pb1[t], o_acc[1][c], 0, 0, 0);
      }
    }

    // staging for tile it+1 had the full compute phase to land
    asm volatile("s_waitcnt vmcnt(0)" ::: "memory");
    __syncthreads();
  }

  // ---- epilogue: O^T accumulator -> contiguous f32x4 stores
  float* obase = outg + (size_t)bhg * (LQ * D) + (size_t)(qtile * BM) * D;
#pragma unroll
  for (int u = 0; u < 2; ++u) {
    const float inv = 1.f / l_r[u];
    float* op = obase + (size_t)(32 * wave + 16 * u + i16) * D;
#pragma unroll
    for (int c = 0; c < 8; ++c) {
      f32x4 r4 = o_acc[u][c] * inv;      // r component = d offset 4*quad+r
      *(f32x4*)(op + 16 * c + 4 * quad) = r4;
    }
  }
}

extern "C" void kernel_launch(void* const* d_in, const int* in_sizes, int n_in,
                              void* d_out, int out_size, void* d_ws, size_t ws_size,
                              hipStream_t stream) {
  const float* q = (const float*)d_in[0];
  const float* k = (const float*)d_in[1];
  const float* v = (const float*)d_in[2];
  float* out = (float*)d_out;
  (void)in_sizes; (void)n_in; (void)out_size; (void)ws_size;

  const size_t kv_elems = (size_t)NKV * SK * D;          // 4.19M
  __bf16* khi = (__bf16*)d_ws;                           // 8.39 MB
  __bf16* klo = khi + kv_elems;                          // 8.39 MB
  __bf16* vt  = klo + kv_elems;                          // 8.39 MB

  conv_k<<<dim3(kv_elems / (256 * 4)), 256, 0, stream>>>(k, khi, klo);
  transpose_v<<<dim3(NKV * 64), 256, 0, stream>>>(v, vt);
  gqa_fwd<<<dim3(8 * (LQ / BM) * 8), 512, 0, stream>>>(q, khi, klo, vt, out);
}

// Round 6
// 398.499 us; speedup vs baseline: 1.0757x; 1.0757x over previous
//
#include <hip/hip_runtime.h>
#include <hip/hip_bf16.h>
#include <math.h>

typedef __bf16 bf16x8 __attribute__((ext_vector_type(8)));
typedef __bf16 bf16x4 __attribute__((ext_vector_type(4)));
typedef float  f32x4  __attribute__((ext_vector_type(4)));

constexpr int D   = 128;
constexpr int LQ  = 2048;
constexpr int SK  = 2048;
constexpr int BM  = 256;  // queries per block (8 waves x 32 rows)
constexpr int BN  = 64;   // keys per iteration
constexpr int NKV = 16;   // B*H distinct KV heads
constexpr int NT  = SK / BN;  // 32

__device__ __forceinline__ void load_lds16(const void* g, void* l) {
  __builtin_amdgcn_global_load_lds((const __attribute__((address_space(1))) unsigned*)g,
                                   (__attribute__((address_space(3))) unsigned*)l, 16, 0, 0);
}

__device__ __forceinline__ f32x4 vmax4(f32x4 a, f32x4 b) {
  f32x4 r;
  r[0] = fmaxf(a[0], b[0]); r[1] = fmaxf(a[1], b[1]);
  r[2] = fmaxf(a[2], b[2]); r[3] = fmaxf(a[3], b[3]);
  return r;
}

// ---- prologue A: K fp32 -> Khi/Klo bf16 (elementwise, coalesced)
__global__ __launch_bounds__(256) void conv_k(const float* __restrict__ k,
                                              __bf16* __restrict__ khi,
                                              __bf16* __restrict__ klo) {
  const size_t i = ((size_t)blockIdx.x * 256 + threadIdx.x) * 4;
  f32x4 a = *(const f32x4*)(k + i);
  bf16x4 hi, lo;
#pragma unroll
  for (int j = 0; j < 4; ++j) {
    hi[j] = (__bf16)a[j];
    lo[j] = (__bf16)(a[j] - (float)hi[j]);
  }
  *(bf16x4*)(khi + i) = hi;
  *(bf16x4*)(klo + i) = lo;
}

// ---- prologue B: V fp32 [bh][s][d] -> Vt bf16 [bh][d][s'] where s' is
// kappa-PERMUTED within each 32-key group: physical slot pi = 8q+4h+r holds
// key w = 16h+4q+r. PV A-fragment then = ONE b128 read with the
// conflict-free chunk pattern (verified round 4/5: SQ_LDS_BANK_CONFLICT = 0).
__global__ __launch_bounds__(256) void transpose_v(const float* __restrict__ v,
                                                   __bf16* __restrict__ vt) {
  const int b    = blockIdx.x;          // 1024 = 16 bh x 64
  const int bh   = b >> 6;
  const int t2   = (b & 63) * 256 + threadIdx.x;  // 0..16383 within bh
  const int d    = t2 & 127;
  const int slot = t2 >> 7;             // 0..127
  const int G    = slot >> 1;           // 32-key group 0..63
  const int h2   = slot & 1;            // which half of the group's slots
  const float* src = v + ((size_t)bh * SK + 32 * G) * D + d;
  bf16x8 o0, o1;
#pragma unroll
  for (int qq = 0; qq < 2; ++qq)
#pragma unroll
    for (int h = 0; h < 2; ++h)
#pragma unroll
      for (int r = 0; r < 4; ++r) {
        const int idx = 8 * qq + 4 * h + r;
        const int w   = 16 * h + 4 * (2 * h2 + qq) + r;
        const __bf16 val = (__bf16)src[(size_t)w * D];
        if (idx < 8) o0[idx] = val; else o1[idx - 8] = val;
      }
  __bf16* dst = vt + ((size_t)bh * D + d) * SK + 32 * G + 16 * h2;
  *(bf16x8*)dst = o0;
  *(bf16x8*)(dst + 8) = o1;
}

// ---- main: flash GQA, 8 waves x 32 q-rows, SOFTWARE-PIPELINED one tile deep:
// body t = { stage(t+2); QK(t+1); PV(t); softmax(t+1) }. PV(t) depends only on
// pb(t) (last body) and V(t) -> its MFMAs are independent of this body's
// QK/softmax chain, so softmax VALU hides under PV matrix-pipe time (rounds
// 2-5 showed MFMA and VALU added SERIALLY: 35%+43% busy, no overlap).
// K double-buffered, V TRIPLE-buffered (112KB LDS, 1 block/CU). QK reads each
// K fragment ONCE feeding both u (round-5's double-read was the regression).
// kappa-baked Vt => conflict-free single-b128 PV reads (verified 0 conflicts).
// exp2-domain softmax (Q pre-scaled by log2e), branchless, no setprio.
__global__ __launch_bounds__(512, 2)
void gqa_fwd(const float* __restrict__ qg, const __bf16* __restrict__ khi_g,
             const __bf16* __restrict__ klo_g, const __bf16* __restrict__ vt_g,
             float* __restrict__ outg)
{
  __shared__ alignas(16) __bf16 Kh[2][BN * D];   // 2 x 16KB
  __shared__ alignas(16) __bf16 Kl[2][BN * D];   // 2 x 16KB
  __shared__ alignas(16) __bf16 Vs[3][D * BN];   // 3 x 16KB  (total 112KB)

  // XCD swizzle: 64 blocks per XCD, each XCD owns 2 KV heads (~3MB L2 set).
  const int bid   = blockIdx.x;
  const int xcd   = bid & 7;
  const int idx   = bid >> 3;           // 0..63
  const int bh    = 2 * xcd + (idx & 1);
  const int grp   = (idx >> 1) & 3;
  const int qtile = idx >> 3;           // 0..7
  const int bhg   = bh * 4 + grp;

  const int tid  = threadIdx.x;
  const int wave = tid >> 6;            // 0..7
  const int lane = tid & 63;
  const int i16  = lane & 15;
  const int quad = lane >> 4;

  const float*  qbase = qg + (size_t)bhg * (LQ * D) + (size_t)(qtile * BM) * D;
  const __bf16* khb   = khi_g + (size_t)bh * (SK * D);
  const __bf16* klb   = klo_g + (size_t)bh * (SK * D);
  const __bf16* vtb   = vt_g + (size_t)bh * (D * SK);   // [d][s-permuted]

  // K: 4 x global_load_lds(16B)/wave, chunk-XOR source swizzle, linear dest
  auto stage_k = [&](int s0, int buf) {
#pragma unroll
    for (int c = 0; c < 2; ++c) {
      const int wc   = 2 * wave + c;          // chunk 0..15 (1KB each)
      const int srow = wc * 4 + (lane >> 4);  // 4 rows of 256B per chunk
      const int jk   = (lane & 15) ^ (srow & 15);
      load_lds16(khb + (size_t)(s0 + srow) * D + 8 * jk, (char*)&Kh[buf][0] + wc * 1024);
      load_lds16(klb + (size_t)(s0 + srow) * D + 8 * jk, (char*)&Kl[buf][0] + wc * 1024);
    }
  };
  // V: 2 x global_load_lds(16B)/wave
  auto stage_v = [&](int s0, int slot) {
#pragma unroll
    for (int c = 0; c < 2; ++c) {
      const int wc   = 2 * wave + c;
      const int drow = wc * 8 + (lane >> 3);  // 8 rows of 128B per chunk
      const int jv   = (lane & 7) ^ (drow & 7);
      load_lds16(vtb + (size_t)drow * SK + s0 + 8 * jv, (char*)&Vs[slot][0] + wc * 1024);
    }
  };

  // prologue: stage tiles 0 and 1 (overlaps the Q-fragment load below)
  stage_k(0, 0);  stage_v(0, 0);
  stage_k(BN, 1); stage_v(BN, 1);

  // ---- Q fragments, persistent hi/lo, pre-scaled by log2(e) for exp2 softmax
  constexpr float LOG2E = 1.44269504089f;
  bf16x8 qhi[2][4], qlo[2][4];
#pragma unroll
  for (int u = 0; u < 2; ++u) {
    const float* qp = qbase + (size_t)(32 * wave + 16 * u + i16) * D + 8 * quad;
#pragma unroll
    for (int t = 0; t < 4; ++t) {
      f32x4 a = *(const f32x4*)(qp + 32 * t);
      f32x4 b = *(const f32x4*)(qp + 32 * t + 4);
#pragma unroll
      for (int j = 0; j < 4; ++j) {
        const float a2 = a[j] * LOG2E;
        const float b2 = b[j] * LOG2E;
        qhi[u][t][j]     = (__bf16)a2;
        qlo[u][t][j]     = (__bf16)(a2 - (float)qhi[u][t][j]);
        qhi[u][t][j + 4] = (__bf16)b2;
        qlo[u][t][j + 4] = (__bf16)(b2 - (float)qhi[u][t][j + 4]);
      }
    }
  }

  f32x4 o_acc[2][8];
#pragma unroll
  for (int u = 0; u < 2; ++u)
#pragma unroll
    for (int c = 0; c < 8; ++c) o_acc[u][c] = (f32x4){0.f, 0.f, 0.f, 0.f};
  float m_r[2] = {-INFINITY, -INFINITY};
  float l_r[2] = {0.f, 0.f};

  // ---- helpers as macros via lambdas (kept inline, branchless) ----
  // QK: sf[u][n] += K(hi/lo) x Q(hi/lo), ONE kh/kl read feeds both u.
  auto qk_tile = [&](const __bf16* khc, const __bf16* klc, f32x4 (&sf)[2][4]) {
#pragma unroll
    for (int n = 0; n < 4; ++n) {
      sf[0][n] = (f32x4){0.f, 0.f, 0.f, 0.f};
      sf[1][n] = (f32x4){0.f, 0.f, 0.f, 0.f};
    }
#pragma unroll
    for (int n = 0; n < 4; ++n) {
#pragma unroll
      for (int t = 0; t < 4; ++t) {
        const int ke = (16 * n + i16) * 128 + 8 * ((4 * t + quad) ^ i16);
        bf16x8 kh = *(const bf16x8*)&khc[ke];
        bf16x8 kl = *(const bf16x8*)&klc[ke];
#pragma unroll
        for (int u = 0; u < 2; ++u) {
          sf[u][n] = __builtin_amdgcn_mfma_f32_16x16x32_bf16(kh, qhi[u][t], sf[u][n], 0, 0, 0);
          sf[u][n] = __builtin_amdgcn_mfma_f32_16x16x32_bf16(kh, qlo[u][t], sf[u][n], 0, 0, 0);
          sf[u][n] = __builtin_amdgcn_mfma_f32_16x16x32_bf16(kl, qhi[u][t], sf[u][n], 0, 0, 0);
        }
      }
    }
  };
  // PV: o_acc[u][c] += V^T x P^T from Vs[slot] (kappa baked in: one b128/frag)
  auto pv_tile = [&](const __bf16* vsc, bf16x8 (&pc)[2][2]) {
#pragma unroll
    for (int c = 0; c < 8; ++c) {
      const int row = 16 * c + i16;
#pragma unroll
      for (int t = 0; t < 2; ++t) {
        bf16x8 av = *(const bf16x8*)&vsc[row * 64 + 8 * ((4 * t + quad) ^ (i16 & 7))];
#pragma unroll
        for (int u = 0; u < 2; ++u)
          o_acc[u][c] = __builtin_amdgcn_mfma_f32_16x16x32_bf16(av, pc[u][t], o_acc[u][c], 0, 0, 0);
      }
    }
  };
  // softmax (log2 domain, branchless): sf -> pb, updates m/l, rescales o_acc.
  auto softmax_tile = [&](f32x4 (&sf)[2][4], bf16x8 (&pn)[2][2]) {
#pragma unroll
    for (int u = 0; u < 2; ++u) {
      f32x4 vm = vmax4(vmax4(sf[u][0], sf[u][1]), vmax4(sf[u][2], sf[u][3]));
      float mx = fmaxf(fmaxf(vm[0], vm[1]), fmaxf(vm[2], vm[3]));
      mx = fmaxf(mx, __shfl_xor(mx, 16, 64));
      mx = fmaxf(mx, __shfl_xor(mx, 32, 64));
      const float mnew  = fmaxf(m_r[u], mx);
      const float alpha = exp2f(m_r[u] - mnew);   // first tile: exp2(-inf)=0
      m_r[u] = mnew;
      f32x4 rs4 = (f32x4){0.f, 0.f, 0.f, 0.f};
      // k-slot j of PV tile t holds key 32t+16(j>>2)+4quad+(j&3): lane-local.
#pragma unroll
      for (int t = 0; t < 2; ++t)
#pragma unroll
        for (int h = 0; h < 2; ++h)
#pragma unroll
          for (int r = 0; r < 4; ++r) {
            const float p   = exp2f(sf[2 * 0 + u][2 * t + h][r] - mnew);
            const __bf16 pv = (__bf16)p;
            pn[u][t][4 * h + r] = pv;
            rs4[r] += (float)pv;   // l consistent with bf16 P fed to P*V
          }
      float rs = (rs4[0] + rs4[1]) + (rs4[2] + rs4[3]);
      rs += __shfl_xor(rs, 16, 64);
      rs += __shfl_xor(rs, 32, 64);
      l_r[u] = l_r[u] * alpha + rs;
#pragma unroll
      for (int c = 0; c < 8; ++c) o_acc[u][c] = o_acc[u][c] * alpha;
    }
  };

  asm volatile("s_waitcnt vmcnt(0)" ::: "memory");
  __syncthreads();

  // ---- pipeline prologue: QK(0) + softmax(0) -> pb_cur
  bf16x8 pb_cur[2][2], pb_nxt[2][2];
  {
    f32x4 sf[2][4];
    qk_tile(&Kh[0][0], &Kl[0][0], sf);
    softmax_tile(sf, pb_cur);
  }
  __syncthreads();   // all waves done reading Kh/Kl[0] before body 0 restages it

  // ---- main loop: body t handles PV(t) + QK(t+1)/softmax(t+1)
  int vcur = 0;      // Vs slot of tile t (wave-uniform scalar)
  for (int t = 0; t < NT - 1; ++t) {
    // stage tile t+2 (wrap on last bodies: re-stages tile 0/1, benign)
    const int s2 = ((t + 2) & (NT - 1)) * BN;
    stage_k(s2, t & 1);
    int vstage = vcur + 2; vstage -= (vstage >= 3) ? 3 : 0;
    stage_v(s2, vstage);

    // QK(t+1) from K buffer (t+1)&1
    f32x4 sf[2][4];
    qk_tile(&Kh[(t + 1) & 1][0], &Kl[(t + 1) & 1][0], sf);

    // PV(t): independent of sf/softmax -> fills matrix pipe under softmax VALU
    pv_tile(&Vs[vcur][0], pb_cur);

    // softmax(t+1) -> pb_nxt (o_acc rescale after PV via data dependence)
    softmax_tile(sf, pb_nxt);

    // rotate pipeline registers / slots
#pragma unroll
    for (int u = 0; u < 2; ++u)
#pragma unroll
      for (int tt = 0; tt < 2; ++tt) pb_cur[u][tt] = pb_nxt[u][tt];
    vcur += 1; vcur -= (vcur >= 3) ? 3 : 0;

    // staging for tile t+2 had the full body to land; barrier republishes
    asm volatile("s_waitcnt vmcnt(0)" ::: "memory");
    __syncthreads();
  }

  // ---- pipeline epilogue: PV(NT-1)
  pv_tile(&Vs[vcur][0], pb_cur);

  // ---- epilogue: O^T accumulator -> contiguous f32x4 stores
  float* obase = outg + (size_t)bhg * (LQ * D) + (size_t)(qtile * BM) * D;
#pragma unroll
  for (int u = 0; u < 2; ++u) {
    const float inv = 1.f / l_r[u];
    float* op = obase + (size_t)(32 * wave + 16 * u + i16) * D;
#pragma unroll
    for (int c = 0; c < 8; ++c) {
      f32x4 r4 = o_acc[u][c] * inv;      // r component = d offset 4*quad+r
      *(f32x4*)(op + 16 * c + 4 * quad) = r4;
    }
  }
}

extern "C" void kernel_launch(void* const* d_in, const int* in_sizes, int n_in,
                              void* d_out, int out_size, void* d_ws, size_t ws_size,
                              hipStream_t stream) {
  const float* q = (const float*)d_in[0];
  const float* k = (const float*)d_in[1];
  const float* v = (const float*)d_in[2];
  float* out = (float*)d_out;
  (void)in_sizes; (void)n_in; (void)out_size; (void)ws_size;

  const size_t kv_elems = (size_t)NKV * SK * D;          // 4.19M
  __bf16* khi = (__bf16*)d_ws;                           // 8.39 MB
  __bf16* klo = khi + kv_elems;                          // 8.39 MB
  __bf16* vt  = klo + kv_elems;                          // 8.39 MB

  conv_k<<<dim3(kv_elems / (256 * 4)), 256, 0, stream>>>(k, khi, klo);
  transpose_v<<<dim3(NKV * 64), 256, 0, stream>>>(v, vt);
  gqa_fwd<<<dim3(8 * (LQ / BM) * 8), 512, 0, stream>>>(q, khi, klo, vt, out);
}

// Round 7
// 384.359 us; speedup vs baseline: 1.1153x; 1.0368x over previous
//
#include <hip/hip_runtime.h>
#include <hip/hip_bf16.h>
#include <math.h>

typedef _Float16 half8 __attribute__((ext_vector_type(8)));
typedef _Float16 half4 __attribute__((ext_vector_type(4)));
typedef float    f32x4 __attribute__((ext_vector_type(4)));

constexpr int D   = 128;
constexpr int LQ  = 2048;
constexpr int SK  = 2048;
constexpr int BM  = 256;  // queries per block (8 waves x 32 rows)
constexpr int BN  = 64;   // keys per iteration
constexpr int NKV = 16;   // B*H distinct KV heads
constexpr int NT  = SK / BN;  // 32

template <int N> struct IC { static constexpr int v = N; };

__device__ __forceinline__ void load_lds16(const void* g, void* l) {
  __builtin_amdgcn_global_load_lds((const __attribute__((address_space(1))) unsigned*)g,
                                   (__attribute__((address_space(3))) unsigned*)l, 16, 0, 0);
}

__device__ __forceinline__ f32x4 vmax4(f32x4 a, f32x4 b) {
  f32x4 r;
  r[0] = fmaxf(a[0], b[0]); r[1] = fmaxf(a[1], b[1]);
  r[2] = fmaxf(a[2], b[2]); r[3] = fmaxf(a[3], b[3]);
  return r;
}

// ---- prologue A: K fp32 -> fp16 (single precision level; the dropped low
// part costs ~sqrt(128)*2^-11 ~ 0.006 abs in scores, ~0.003 in output.
// P/V move bf16->fp16 below, cutting the previously-dominant P rounding 4x.)
__global__ __launch_bounds__(256) void conv_k16(const float* __restrict__ k,
                                                _Float16* __restrict__ kh) {
  const size_t i = ((size_t)blockIdx.x * 256 + threadIdx.x) * 4;
  f32x4 a = *(const f32x4*)(k + i);
  half4 h;
#pragma unroll
  for (int j = 0; j < 4; ++j) h[j] = (_Float16)a[j];
  *(half4*)(kh + i) = h;
}

// ---- prologue B: V fp32 [bh][s][d] -> Vt fp16 [bh][d][s'] where s' is
// kappa-PERMUTED within each 32-key group: physical slot pi = 8q+4h+r holds
// key w = 16h+4q+r. PV A-fragment then = ONE b128 read with the
// conflict-free chunk pattern (verified rounds 4-6: SQ_LDS_BANK_CONFLICT = 0).
__global__ __launch_bounds__(256) void transpose_v(const float* __restrict__ v,
                                                   _Float16* __restrict__ vt) {
  const int b    = blockIdx.x;          // 1024 = 16 bh x 64
  const int bh   = b >> 6;
  const int t2   = (b & 63) * 256 + threadIdx.x;  // 0..16383 within bh
  const int d    = t2 & 127;
  const int slot = t2 >> 7;             // 0..127
  const int G    = slot >> 1;           // 32-key group 0..63
  const int h2   = slot & 1;            // which half of the group's slots
  const float* src = v + ((size_t)bh * SK + 32 * G) * D + d;
  half8 o0, o1;
#pragma unroll
  for (int qq = 0; qq < 2; ++qq)
#pragma unroll
    for (int h = 0; h < 2; ++h)
#pragma unroll
      for (int r = 0; r < 4; ++r) {
        const int idx = 8 * qq + 4 * h + r;
        const int w   = 16 * h + 4 * (2 * h2 + qq) + r;
        const _Float16 val = (_Float16)src[(size_t)w * D];
        if (idx < 8) o0[idx] = val; else o1[idx - 8] = val;
      }
  _Float16* dst = vt + ((size_t)bh * D + d) * SK + 32 * G + 16 * h2;
  *(half8*)dst = o0;
  *(half8*)(dst + 8) = o1;
}

// ---- main: flash GQA, 8 waves x 32 q-rows, fp16 datapath.
// QK = kh x (qhi + qlo): 2 MFMAs per fragment (was 3 with bf16 hi/lo K),
// and NO Kl tile -> LDS reads 32 b128/wave/iter (was 48), LDS 64KB total.
// Software pipeline (R6): body t = { stage; QK(t+1); PV(t); softmax(t+1) }.
// Bodies unrolled x2 -> all buffer indices & pb sets compile-time (no
// buffer-select VALU, no pb rotate). One vmcnt(0)+barrier per body.
// kappa-baked Vt => conflict-free single-b128 PV reads. exp2-domain softmax.
__global__ __launch_bounds__(512, 2)
void gqa_fwd(const float* __restrict__ qg, const _Float16* __restrict__ kh_g,
             const _Float16* __restrict__ vt_g, float* __restrict__ outg)
{
  __shared__ alignas(16) _Float16 Kh[2][BN * D];  // 2 x 16KB
  __shared__ alignas(16) _Float16 Vs[2][D * BN];  // 2 x 16KB  (total 64KB)

  // XCD swizzle: 64 blocks per XCD, each XCD owns 2 KV heads (~2MB L2 set).
  const int bid   = blockIdx.x;
  const int xcd   = bid & 7;
  const int idx   = bid >> 3;           // 0..63
  const int bh    = 2 * xcd + (idx & 1);
  const int grp   = (idx >> 1) & 3;
  const int qtile = idx >> 3;           // 0..7
  const int bhg   = bh * 4 + grp;

  const int tid  = threadIdx.x;
  const int wave = tid >> 6;            // 0..7
  const int lane = tid & 63;
  const int i16  = lane & 15;
  const int quad = lane >> 4;

  const float*    qbase = qg + (size_t)bhg * (LQ * D) + (size_t)(qtile * BM) * D;
  const _Float16* khb   = kh_g + (size_t)bh * (SK * D);
  const _Float16* vtb   = vt_g + (size_t)bh * (D * SK);   // [d][s-permuted]

  // K: 2 x global_load_lds(16B)/wave, chunk-XOR source swizzle, linear dest
  auto stage_k = [&](int s0, _Float16* dst) {
#pragma unroll
    for (int c = 0; c < 2; ++c) {
      const int wc   = 2 * wave + c;          // chunk 0..15 (1KB each)
      const int srow = wc * 4 + (lane >> 4);  // 4 rows of 256B per chunk
      const int jk   = (lane & 15) ^ (srow & 15);
      load_lds16(khb + (size_t)(s0 + srow) * D + 8 * jk, (char*)dst + wc * 1024);
    }
  };
  // V: 2 x global_load_lds(16B)/wave
  auto stage_v = [&](int s0, _Float16* dst) {
#pragma unroll
    for (int c = 0; c < 2; ++c) {
      const int wc   = 2 * wave + c;
      const int drow = wc * 8 + (lane >> 3);  // 8 rows of 128B per chunk
      const int jv   = (lane & 7) ^ (drow & 7);
      load_lds16(vtb + (size_t)drow * SK + s0 + 8 * jv, (char*)dst + wc * 1024);
    }
  };

  // prologue staging: K(0), K(1), V(0)   (overlaps the Q-fragment load below)
  stage_k(0, &Kh[0][0]);
  stage_k(BN, &Kh[1][0]);
  stage_v(0, &Vs[0][0]);

  // ---- Q fragments, persistent hi/lo fp16, pre-scaled by log2(e)
  constexpr float LOG2E = 1.44269504089f;
  half8 qhi[2][4], qlo[2][4];
#pragma unroll
  for (int u = 0; u < 2; ++u) {
    const float* qp = qbase + (size_t)(32 * wave + 16 * u + i16) * D + 8 * quad;
#pragma unroll
    for (int t = 0; t < 4; ++t) {
      f32x4 a = *(const f32x4*)(qp + 32 * t);
      f32x4 b = *(const f32x4*)(qp + 32 * t + 4);
#pragma unroll
      for (int j = 0; j < 4; ++j) {
        const float a2 = a[j] * LOG2E;
        const float b2 = b[j] * LOG2E;
        qhi[u][t][j]     = (_Float16)a2;
        qlo[u][t][j]     = (_Float16)(a2 - (float)qhi[u][t][j]);
        qhi[u][t][j + 4] = (_Float16)b2;
        qlo[u][t][j + 4] = (_Float16)(b2 - (float)qhi[u][t][j + 4]);
      }
    }
  }

  f32x4 o_acc[2][8];
#pragma unroll
  for (int u = 0; u < 2; ++u)
#pragma unroll
    for (int c = 0; c < 8; ++c) o_acc[u][c] = (f32x4){0.f, 0.f, 0.f, 0.f};
  float m_r[2] = {-INFINITY, -INFINITY};
  float l_r[2] = {0.f, 0.f};

  // ---- helpers (branchless, inline) ----
  auto qk_tile = [&](const _Float16* khc, f32x4 (&sf)[2][4]) {
#pragma unroll
    for (int n = 0; n < 4; ++n) {
      sf[0][n] = (f32x4){0.f, 0.f, 0.f, 0.f};
      sf[1][n] = (f32x4){0.f, 0.f, 0.f, 0.f};
    }
#pragma unroll
    for (int n = 0; n < 4; ++n) {
#pragma unroll
      for (int t = 0; t < 4; ++t) {
        const int ke = (16 * n + i16) * 128 + 8 * ((4 * t + quad) ^ i16);
        half8 kh = *(const half8*)&khc[ke];
#pragma unroll
        for (int u = 0; u < 2; ++u) {
          sf[u][n] = __builtin_amdgcn_mfma_f32_16x16x32_f16(kh, qhi[u][t], sf[u][n], 0, 0, 0);
          sf[u][n] = __builtin_amdgcn_mfma_f32_16x16x32_f16(kh, qlo[u][t], sf[u][n], 0, 0, 0);
        }
      }
    }
  };
  auto pv_tile = [&](const _Float16* vsc, half8 (&pc)[2][2]) {
#pragma unroll
    for (int c = 0; c < 8; ++c) {
      const int row = 16 * c + i16;
#pragma unroll
      for (int t = 0; t < 2; ++t) {
        half8 av = *(const half8*)&vsc[row * 64 + 8 * ((4 * t + quad) ^ (i16 & 7))];
#pragma unroll
        for (int u = 0; u < 2; ++u)
          o_acc[u][c] = __builtin_amdgcn_mfma_f32_16x16x32_f16(av, pc[u][t], o_acc[u][c], 0, 0, 0);
      }
    }
  };
  auto softmax_tile = [&](f32x4 (&sf)[2][4], half8 (&pn)[2][2]) {
#pragma unroll
    for (int u = 0; u < 2; ++u) {
      f32x4 vm = vmax4(vmax4(sf[u][0], sf[u][1]), vmax4(sf[u][2], sf[u][3]));
      float mx = fmaxf(fmaxf(vm[0], vm[1]), fmaxf(vm[2], vm[3]));
      mx = fmaxf(mx, __shfl_xor(mx, 16, 64));
      mx = fmaxf(mx, __shfl_xor(mx, 32, 64));
      const float mnew  = fmaxf(m_r[u], mx);
      const float alpha = exp2f(m_r[u] - mnew);   // first tile: exp2(-inf)=0
      m_r[u] = mnew;
      f32x4 rs4 = (f32x4){0.f, 0.f, 0.f, 0.f};
      // k-slot j of PV tile t holds key 32t+16(j>>2)+4quad+(j&3): lane-local.
#pragma unroll
      for (int t = 0; t < 2; ++t)
#pragma unroll
        for (int h = 0; h < 2; ++h)
#pragma unroll
          for (int r = 0; r < 4; ++r) {
            const float p     = exp2f(sf[u][2 * t + h][r] - mnew);
            const _Float16 pv = (_Float16)p;
            pn[u][t][4 * h + r] = pv;
            rs4[r] += (float)pv;   // l consistent with fp16 P fed to P*V
          }
      float rs = (rs4[0] + rs4[1]) + (rs4[2] + rs4[3]);
      rs += __shfl_xor(rs, 16, 64);
      rs += __shfl_xor(rs, 32, 64);
      l_r[u] = l_r[u] * alpha + rs;
#pragma unroll
      for (int c = 0; c < 8; ++c) o_acc[u][c] = o_acc[u][c] * alpha;
    }
  };

  asm volatile("s_waitcnt vmcnt(0)" ::: "memory");
  __syncthreads();

  // ---- pipeline prologue: QK(0) + softmax(0) -> pbA
  half8 pbA[2][2], pbB[2][2];
  {
    f32x4 sf[2][4];
    qk_tile(&Kh[0][0], sf);
    softmax_tile(sf, pbA);
  }
  __syncthreads();   // all waves done reading Kh[0] before body 0 restages it

  // ---- body: t with CUR = t&1 compile-time. Layout proven hazard-free by
  // the end-of-body vmcnt(0)+barrier (each buffer's last read and next
  // overwrite are in different bodies).
  auto body = [&](int t, auto curc, half8 (&pbU)[2][2], half8 (&pbF)[2][2]) {
    constexpr int CUR = decltype(curc)::v;
    stage_k(((t + 2) & (NT - 1)) * BN, &Kh[CUR][0]);   // K(t+2)
    stage_v((t + 1) * BN, &Vs[CUR ^ 1][0]);            // V(t+1)
    f32x4 sf[2][4];
    qk_tile(&Kh[CUR ^ 1][0], sf);                      // QK(t+1)
    pv_tile(&Vs[CUR][0], pbU);                         // PV(t), indep of sf
    softmax_tile(sf, pbF);                             // softmax(t+1)
    asm volatile("s_waitcnt vmcnt(0)" ::: "memory");
    __syncthreads();
  };

  // 31 bodies (t=0..30), unrolled x2: 15 pairs + final even body
  for (int tp = 0; tp < 15; ++tp) {
    body(2 * tp,     IC<0>{}, pbA, pbB);
    body(2 * tp + 1, IC<1>{}, pbB, pbA);
  }
  body(30, IC<0>{}, pbA, pbB);

  // ---- pipeline epilogue: PV(31) from Vs[1], pbB
  pv_tile(&Vs[1][0], pbB);

  // ---- epilogue: O^T accumulator -> contiguous f32x4 stores
  float* obase = outg + (size_t)bhg * (LQ * D) + (size_t)(qtile * BM) * D;
#pragma unroll
  for (int u = 0; u < 2; ++u) {
    const float inv = 1.f / l_r[u];
    float* op = obase + (size_t)(32 * wave + 16 * u + i16) * D;
#pragma unroll
    for (int c = 0; c < 8; ++c) {
      f32x4 r4 = o_acc[u][c] * inv;      // r component = d offset 4*quad+r
      *(f32x4*)(op + 16 * c + 4 * quad) = r4;
    }
  }
}

extern "C" void kernel_launch(void* const* d_in, const int* in_sizes, int n_in,
                              void* d_out, int out_size, void* d_ws, size_t ws_size,
                              hipStream_t stream) {
  const float* q = (const float*)d_in[0];
  const float* k = (const float*)d_in[1];
  const float* v = (const float*)d_in[2];
  float* out = (float*)d_out;
  (void)in_sizes; (void)n_in; (void)out_size; (void)ws_size;

  const size_t kv_elems = (size_t)NKV * SK * D;          // 4.19M
  _Float16* kh = (_Float16*)d_ws;                        // 8.39 MB
  _Float16* vt = kh + kv_elems;                          // 8.39 MB

  conv_k16<<<dim3(kv_elems / (256 * 4)), 256, 0, stream>>>(k, kh);
  transpose_v<<<dim3(NKV * 64), 256, 0, stream>>>(v, vt);
  gqa_fwd<<<dim3(8 * (LQ / BM) * 8), 512, 0, stream>>>(q, kh, vt, out);
}